// Round 1
// baseline (344.080 us; speedup 1.0000x reference)
//
#include <hip/hip_runtime.h>

#define BB 4
#define AA 512
#define DD 729
#define HH 512
#define WW 512

__global__ __launch_bounds__(256) void bp_kernel(
    const float* __restrict__ sino,
    const float* __restrict__ vol_origin,
    const float* __restrict__ det_origin,
    const float* __restrict__ vol_spacing,
    const float* __restrict__ det_spacing,
    const float* __restrict__ angles,
    float* __restrict__ out)
{
    __shared__ float s_cu[AA];
    __shared__ float s_su[AA];

    const int tid = threadIdx.y * 16 + threadIdx.x;
    const float inv_ds = 1.0f / det_spacing[0];

    // Per-block precompute of per-angle direction (scaled by 1/det_spacing).
    for (int a = tid; a < AA; a += 256) {
        float th = angles[a];
        s_cu[a] = cosf(th) * inv_ds;
        s_su[a] = sinf(th) * inv_ds;
    }
    __syncthreads();

    const int ix = blockIdx.x * 16 + threadIdx.x;
    const int iy = blockIdx.y * 16 + threadIdx.y;
    const int b  = blockIdx.z;

    const float xw  = vol_origin[1] + (float)ix * vol_spacing[1];
    const float yw  = vol_origin[0] + (float)iy * vol_spacing[0];
    const float off = -det_origin[0] * inv_ds;

    const float* __restrict__ srow = sino + (size_t)b * AA * DD;

    float acc0 = 0.f, acc1 = 0.f;

    #pragma unroll 4
    for (int a = 0; a < AA; a += 2) {
        // angle a
        {
            float u    = fmaf(xw, s_cu[a], fmaf(yw, s_su[a], off));
            float u0   = floorf(u);
            float frac = u - u0;
            int   i0   = (int)u0;
            int   i1   = i0 + 1;
            int   i0c  = min(max(i0, 0), DD - 1);
            int   i1c  = min(max(i1, 0), DD - 1);
            float v0   = srow[i0c];
            float v1   = srow[i1c];
            float w0   = (i0 >= 0 && i0 < DD) ? (1.0f - frac) : 0.0f;
            float w1   = (i1 >= 0 && i1 < DD) ? frac          : 0.0f;
            acc0 = fmaf(w0, v0, acc0);
            acc0 = fmaf(w1, v1, acc0);
        }
        // angle a+1
        {
            const float* __restrict__ srow1 = srow + DD;
            float u    = fmaf(xw, s_cu[a + 1], fmaf(yw, s_su[a + 1], off));
            float u0   = floorf(u);
            float frac = u - u0;
            int   i0   = (int)u0;
            int   i1   = i0 + 1;
            int   i0c  = min(max(i0, 0), DD - 1);
            int   i1c  = min(max(i1, 0), DD - 1);
            float v0   = srow1[i0c];
            float v1   = srow1[i1c];
            float w0   = (i0 >= 0 && i0 < DD) ? (1.0f - frac) : 0.0f;
            float w1   = (i1 >= 0 && i1 < DD) ? frac          : 0.0f;
            acc1 = fmaf(w0, v0, acc1);
            acc1 = fmaf(w1, v1, acc1);
        }
        srow += 2 * DD;
    }

    out[((size_t)b * HH + iy) * WW + ix] = acc0 + acc1;
}

extern "C" void kernel_launch(void* const* d_in, const int* in_sizes, int n_in,
                              void* d_out, int out_size, void* d_ws, size_t ws_size,
                              hipStream_t stream) {
    const float* sino        = (const float*)d_in[0];
    // d_in[1] = volume_shape (int64) — compile-time constants HH/WW used.
    const float* vol_origin  = (const float*)d_in[2];
    const float* det_origin  = (const float*)d_in[3];
    const float* vol_spacing = (const float*)d_in[4];
    const float* det_spacing = (const float*)d_in[5];
    const float* angles      = (const float*)d_in[6];
    float* out = (float*)d_out;

    dim3 block(16, 16, 1);
    dim3 grid(WW / 16, HH / 16, BB);
    bp_kernel<<<grid, block, 0, stream>>>(sino, vol_origin, det_origin,
                                          vol_spacing, det_spacing, angles, out);
}